// Round 12
// baseline (608.485 us; speedup 1.0000x reference)
//
#include <hip/hip_runtime.h>
#include <hip/hip_bf16.h>
#include <math.h>

#define NB 16384
#define NH 16
#define ND 256
#define NM 1024
#define BM 128           // rows per block
#define MB 64            // m-chunk
#define NCH (NM / MB)    // 16

typedef float f32x4 __attribute__((ext_vector_type(4)));
typedef float f32x16 __attribute__((ext_vector_type(16)));
typedef short bf16x8 __attribute__((ext_vector_type(8)));
typedef unsigned short u16;
typedef unsigned int u32;

__device__ __forceinline__ u16 f2bf(float f) {
  union { float f; unsigned u; } v; v.f = f;
  unsigned r = v.u + 0x7FFFu + ((v.u >> 16) & 1u);
  return (u16)(r >> 16);
}

// UpF[h]: granule byte off = mc*32768 + kh*1024 + m*16, kh in [0,32), m in [0,64)
//   elems e: up[h][kh*8+e][mc*64+m]   (up fp32 [H][256][1024])
__global__ __launch_bounds__(256) void prep_up(const float* __restrict__ src,
                                               u16* __restrict__ dst) {
  __shared__ float tile[64][65];
  const int h = blockIdx.z;
  const int m0 = blockIdx.x * 64, d0 = blockIdx.y * 64;
  const int tr = threadIdx.x >> 6, tc = threadIdx.x & 63;
  const float* s = src + (size_t)h * ND * NM;
#pragma unroll
  for (int i = 0; i < 16; ++i) {
    int r = i * 4 + tr;
    tile[r][tc] = s[(size_t)(d0 + r) * NM + m0 + tc];
  }
  __syncthreads();
  char* dh = (char*)dst + (size_t)h * NM * ND * 2;
#pragma unroll
  for (int g = 0; g < 2; ++g) {
    int gi = g * 256 + threadIdx.x;
    int kh_l = gi >> 6, m_l = gi & 63;
    bf16x8 o;
#pragma unroll
    for (int e = 0; e < 8; ++e) o[e] = (short)f2bf(tile[kh_l * 8 + e][m_l]);
    *(bf16x8*)(dh + (size_t)(m0 >> 6) * 32768 + (size_t)((d0 >> 3) + kh_l) * 1024 + m_l * 16) = o;
  }
}

// DownF[h]: granule byte off = mc*32768 + kh*4096 + d*16, kh in [0,8), d in [0,256)
//   elems e: down[h][mc*64+kh*8+e][d]   (down fp32 [H][1024][256])
__global__ __launch_bounds__(256) void prep_down(const float* __restrict__ src,
                                                 u16* __restrict__ dst) {
  __shared__ float tile[64][65];
  const int h = blockIdx.z;
  const int mc = blockIdx.x, d0 = blockIdx.y * 64;
  const int tr = threadIdx.x >> 6, tc = threadIdx.x & 63;
  const float* s = src + (size_t)h * NM * ND;
#pragma unroll
  for (int i = 0; i < 16; ++i) {
    int r = i * 4 + tr;
    tile[r][tc] = s[(size_t)(mc * 64 + r) * ND + d0 + tc];
  }
  __syncthreads();
  char* dh = (char*)dst + (size_t)h * NM * ND * 2;
#pragma unroll
  for (int g = 0; g < 2; ++g) {
    int gi = g * 256 + threadIdx.x;
    int kh_l = gi >> 6, d_l = gi & 63;
    bf16x8 o;
#pragma unroll
    for (int e = 0; e < 8; ++e) o[e] = (short)f2bf(tile[kh_l * 8 + e][d_l]);
    *(bf16x8*)(dh + (size_t)mc * 32768 + (size_t)kh_l * 4096 + (size_t)(d0 + d_l) * 16) = o;
  }
}

// xp[b][i] = bf16(x[b][perm[i]])
__global__ __launch_bounds__(1024) void permute_x(const float* __restrict__ x,
                                                  const int* __restrict__ perm,
                                                  u16* __restrict__ xp) {
  const int b = blockIdx.x;
  const int t = threadIdx.x;
  const float* xr = x + (size_t)b * 4096;
  int4 p = *(const int4*)(perm + t * 4);
  ushort4 o;
  o.x = f2bf(xr[p.x]); o.y = f2bf(xr[p.y]);
  o.z = f2bf(xr[p.z]); o.w = f2bf(xr[p.w]);
  *(ushort4*)(xp + (size_t)b * 4096 + t * 4) = o;
}

// out[b][j] = out[b][unperm[j]] (in place, one row per block)
__global__ __launch_bounds__(1024) void unpermute_out(float* __restrict__ out,
                                                      const int* __restrict__ unperm) {
  __shared__ float row[4096];
  const int b = blockIdx.x;
  const int t = threadIdx.x;
  float* orow = out + (size_t)b * 4096;
  *(f32x4*)(row + t * 4) = *(const f32x4*)(orow + t * 4);
  __syncthreads();
  int4 u = *(const int4*)(unperm + t * 4);
  f32x4 v;
  v.x = row[u.x]; v.y = row[u.y]; v.z = row[u.z]; v.w = row[u.w];
  *(f32x4*)(orow + t * 4) = v;
}

// 16-wave PRODUCER/CONSUMER MLP (R10 structure, best measured: 404us) with
// the R10 spill fixed: launch_bounds(1024, 2). R10's (1024,4) made the
// allocator target 64 VGPR (aiming at 8 waves/SIMD that the 160KB LDS makes
// impossible anyway -- 1 block/CU = 4 waves/SIMD regardless) and the A-branch
// working set (xr 64 + pa + addressing) spilled: WRITE_SIZE 262->335MB,
// FETCH +17MB, scratch in every region's critical path. Cap 256 removes it;
// occupancy is unchanged (LDS-bound). Also: pa split into 2 independent
// 8-chains (+16 VGPR, now affordable) so A's MFMA issue isn't chained 16 deep.
__global__ __launch_bounds__(1024, 2) void mlp_fused(
    const u16* __restrict__ xp,
    const u16* __restrict__ upF,
    const u16* __restrict__ downF,
    float* __restrict__ out) {
  __shared__ __align__(16) u16 Us[2][MB * ND];   // 2x32KB [kh32][m64][8]
  __shared__ __align__(16) u16 Ds[2][ND * MB];   // 2x32KB [kh8][d256][8]
  __shared__ __align__(16) u16 Ps[2][BM * MB];   // 2x16KB [kh8][r128][8]

  const int h   = blockIdx.y;
  const int rb  = blockIdx.x;
  const int tid = threadIdx.x;
  const int w   = tid >> 6;
  const int l   = tid & 63;
  const int lo  = l & 31;
  const int hi  = l >> 5;
  const int row0 = rb * BM;

  const char* upH = (const char*)upF + (size_t)h * NM * ND * 2;
  const char* dnH = (const char*)downF + (size_t)h * NM * ND * 2;

  // ---- prologue: all 16 waves stage Us(0) (2 insts/thread), then barrier
  {
#pragma unroll
    for (int i = 0; i < 2; ++i) {
      int t = i * 1024 + tid;
      __builtin_amdgcn_global_load_lds(
          (const __attribute__((address_space(1))) void*)(upH + (size_t)t * 16),
          (__attribute__((address_space(3))) void*)((char*)&Us[0][0] + (size_t)t * 16),
          16, 0, 0);
    }
  }
  asm volatile("s_waitcnt vmcnt(0)" ::: "memory");
  __builtin_amdgcn_s_barrier();

  if (w < 8) {
    // ================= producer (A) =================
    const int rtA = w & 3;    // 32-row tile
    const int mt  = w >> 2;   // 32-m tile of the 64-m chunk

    // X fragments: lane = x-row (rtA*32+lo), k = ks*16 + hi*8 + e. 64 VGPR.
    bf16x8 xr[16];
    {
      const char* px = (const char*)(xp + (size_t)(row0 + rtA * 32 + lo) * 4096 + h * ND);
#pragma unroll
      for (int ks = 0; ks < 16; ++ks)
        xr[ks] = *(const bf16x8*)(px + ks * 32 + hi * 16);
    }
    char* const psW = (char*)&Ps[0][0] + (size_t)(rtA * 32 + lo) * 16 + hi * 8;

    for (int i = 0; i < NCH; ++i) {
      const int c = i & 1;
      // stage Us(i+1) -> buf c^1 (A-threads: tid in [0,512), 4 insts)
      if (i + 1 < NCH) {
        const char* src = upH + (size_t)(i + 1) * 32768;
#pragma unroll
        for (int j = 0; j < 4; ++j) {
          int t = j * 512 + tid;
          __builtin_amdgcn_global_load_lds(
              (const __attribute__((address_space(1))) void*)(src + (size_t)t * 16),
              (__attribute__((address_space(3))) void*)((char*)&Us[c ^ 1][0] + (size_t)t * 16),
              16, 0, 0);
        }
      }

      // A(i): P^T[32m x 32r] = Up-frags @ X-frags, 2 independent 8-chains
      f32x16 pa0, pa1;
#pragma unroll
      for (int e = 0; e < 16; ++e) { pa0[e] = 0.f; pa1[e] = 0.f; }
      {
        const char* ub = (const char*)&Us[c][0] + (size_t)(mt * 32 + lo) * 16 + hi * 1024;
        __builtin_amdgcn_s_setprio(1);
#pragma unroll
        for (int ks = 0; ks < 8; ++ks) {
          bf16x8 av0 = *(const bf16x8*)(ub + (size_t)(2 * ks) * 2048);
          bf16x8 av1 = *(const bf16x8*)(ub + (size_t)(2 * ks + 1) * 2048);
          pa0 = __builtin_amdgcn_mfma_f32_32x32x16_bf16(av0, xr[2 * ks], pa0, 0, 0, 0);
          pa1 = __builtin_amdgcn_mfma_f32_32x32x16_bf16(av1, xr[2 * ks + 1], pa1, 0, 0, 0);
        }
        __builtin_amdgcn_s_setprio(0);
      }
      f32x16 pa = pa0 + pa1;

      // gelu -> pack -> 4x ds_write_b64 into Ps[c]
      // pa[4g+e] = P[r=rtA*32+lo][m = mt*32 + g*8 + hi*4 + e]
#pragma unroll
      for (int g = 0; g < 4; ++g) {
        float gv[4];
#pragma unroll
        for (int e = 0; e < 4; ++e) {
          float v = pa[g * 4 + e];
          float p = __builtin_fmaf(0.1029433f, v * v, 2.3022082f);
          float ex = __builtin_amdgcn_exp2f(v * p);
          float r = __builtin_amdgcn_rcpf(ex + 1.0f);
          gv[e] = __builtin_fmaf(-v, r, v);
        }
        u32 w0, w1;
        asm("v_cvt_pk_bf16_f32 %0, %1, %2" : "=v"(w0) : "v"(gv[0]), "v"(gv[1]));
        asm("v_cvt_pk_bf16_f32 %0, %1, %2" : "=v"(w1) : "v"(gv[2]), "v"(gv[3]));
        uint2 pk; pk.x = w0; pk.y = w1;
        *(uint2*)(psW + (size_t)c * (BM * MB * 2) + (size_t)(mt * 4 + g) * 2048) = pk;
      }

      __builtin_amdgcn_sched_barrier(0);
      asm volatile("s_waitcnt lgkmcnt(0)" ::: "memory");   // Ps published
      asm volatile("s_waitcnt vmcnt(0)" ::: "memory");     // Us(i+1) landed
      __builtin_amdgcn_s_barrier();
      __builtin_amdgcn_sched_barrier(0);
    }
    // A-waves done (out written by B-waves)
  } else {
    // ================= consumer (B) =================
    const int wb  = w - 8;
    const int rtp = wb & 1;   // 64-row half
    const int dq  = wb >> 1;  // 64-d quarter
    const int tb  = tid - 512;

    f32x16 ca[2][2];   // [rt2][dt] 32x32 tiles: 64r x 64d -> 64 VGPR
#pragma unroll
    for (int rt2 = 0; rt2 < 2; ++rt2)
#pragma unroll
      for (int dt = 0; dt < 2; ++dt)
#pragma unroll
        for (int e = 0; e < 16; ++e)
          ca[rt2][dt][e] = 0.f;

    for (int i = 0; i < NCH; ++i) {
      const int c = i & 1;
      // stage Ds(i) -> buf c (B-threads, 4 insts)
      {
        const char* src = dnH + (size_t)i * 32768;
#pragma unroll
        for (int j = 0; j < 4; ++j) {
          int t = j * 512 + tb;
          __builtin_amdgcn_global_load_lds(
              (const __attribute__((address_space(1))) void*)(src + (size_t)t * 16),
              (__attribute__((address_space(3))) void*)((char*)&Ds[c][0] + (size_t)t * 16),
              16, 0, 0);
        }
      }

      // B(i-1): C += Ps[c^1] @ Ds[c^1]
      if (i > 0) {
        const char* psb = (const char*)&Ps[c ^ 1][0];
        const char* dsb = (const char*)&Ds[c ^ 1][0];
        __builtin_amdgcn_s_setprio(1);
#pragma unroll
        for (int ks = 0; ks < 4; ++ks) {
          const size_t khp = (size_t)(ks * 2 + hi);
          bf16x8 a0 = *(const bf16x8*)(psb + khp * 2048 + (size_t)(rtp * 64 + lo) * 16);
          bf16x8 a1 = *(const bf16x8*)(psb + khp * 2048 + (size_t)(rtp * 64 + 32 + lo) * 16);
#pragma unroll
          for (int dt = 0; dt < 2; ++dt) {
            bf16x8 bv = *(const bf16x8*)(dsb + khp * 4096 + (size_t)(dq * 64 + dt * 32 + lo) * 16);
            ca[0][dt] = __builtin_amdgcn_mfma_f32_32x32x16_bf16(a0, bv, ca[0][dt], 0, 0, 0);
            ca[1][dt] = __builtin_amdgcn_mfma_f32_32x32x16_bf16(a1, bv, ca[1][dt], 0, 0, 0);
          }
        }
        __builtin_amdgcn_s_setprio(0);
      }

      __builtin_amdgcn_sched_barrier(0);
      asm volatile("s_waitcnt vmcnt(0)" ::: "memory");     // Ds(i) landed
      __builtin_amdgcn_s_barrier();
      __builtin_amdgcn_sched_barrier(0);
    }

    // final B(NCH-1): Ps[1], Ds[1]
    {
      const int c = (NCH - 1) & 1;
      const char* psb = (const char*)&Ps[c][0];
      const char* dsb = (const char*)&Ds[c][0];
      __builtin_amdgcn_s_setprio(1);
#pragma unroll
      for (int ks = 0; ks < 4; ++ks) {
        const size_t khp = (size_t)(ks * 2 + hi);
        bf16x8 a0 = *(const bf16x8*)(psb + khp * 2048 + (size_t)(rtp * 64 + lo) * 16);
        bf16x8 a1 = *(const bf16x8*)(psb + khp * 2048 + (size_t)(rtp * 64 + 32 + lo) * 16);
#pragma unroll
        for (int dt = 0; dt < 2; ++dt) {
          bf16x8 bv = *(const bf16x8*)(dsb + khp * 4096 + (size_t)(dq * 64 + dt * 32 + lo) * 16);
          ca[0][dt] = __builtin_amdgcn_mfma_f32_32x32x16_bf16(a0, bv, ca[0][dt], 0, 0, 0);
          ca[1][dt] = __builtin_amdgcn_mfma_f32_32x32x16_bf16(a1, bv, ca[1][dt], 0, 0, 0);
        }
      }
      __builtin_amdgcn_s_setprio(0);
    }

    // epilogue: out[b][h*256+d], coalesced across lanes (32 consecutive d)
    // C-layout 32x32: col d = lo, row = (reg&3) + 8*(reg>>2) + 4*hi.
#pragma unroll
    for (int rt2 = 0; rt2 < 2; ++rt2)
#pragma unroll
      for (int dt = 0; dt < 2; ++dt) {
        const int d = h * ND + dq * 64 + dt * 32 + lo;
#pragma unroll
        for (int reg = 0; reg < 16; ++reg) {
          int r = rtp * 64 + rt2 * 32 + (reg & 3) + 8 * (reg >> 2) + 4 * hi;
          out[(size_t)(row0 + r) * 4096 + d] = ca[rt2][dt][reg];
        }
      }
  }
}

extern "C" void kernel_launch(void* const* d_in, const int* in_sizes, int n_in,
                              void* d_out, int out_size, void* d_ws, size_t ws_size,
                              hipStream_t stream) {
  const float* x    = (const float*)d_in[0];
  const float* up   = (const float*)d_in[1];
  const float* down = (const float*)d_in[2];
  const int* perm   = (const int*)d_in[3];
  const int* unperm = (const int*)d_in[4];
  float* out = (float*)d_out;

  u16* upF   = (u16*)d_ws;                                   // 8 MB
  u16* downF = upF + (size_t)NH * NM * ND;                   // 8 MB
  u16* xp    = downF + (size_t)NH * NM * ND;                 // 128 MB

  // weights -> fragment-granule order (one-time, coalesced tile transposes)
  prep_up<<<dim3(NM / 64, ND / 64, NH), 256, 0, stream>>>(up, upF);
  prep_down<<<dim3(NM / 64, ND / 64, NH), 256, 0, stream>>>(down, downF);
  // xp[b][i] = bf16(x[b][perm[i]])
  permute_x<<<NB, 1024, 0, stream>>>(x, perm, xp);
  // main fused MLP: 1024 thr (8 producer + 8 consumer waves), 160KB LDS.
  mlp_fused<<<dim3(NB / BM, NH), 1024, 0, stream>>>(xp, upF, downF, out);
  // in-place feature unpermute
  unpermute_out<<<NB, 1024, 0, stream>>>(out, unperm);
}

// Round 13
// 592.675 us; speedup vs baseline: 1.0267x; 1.0267x over previous
//
#include <hip/hip_runtime.h>
#include <hip/hip_bf16.h>
#include <math.h>

#define NB 16384
#define NH 16
#define ND 256
#define NM 1024
#define BM 128           // rows per block
#define MB 64            // m-chunk
#define NCH (NM / MB)    // 16

typedef float f32x4 __attribute__((ext_vector_type(4)));
typedef float f32x16 __attribute__((ext_vector_type(16)));
typedef short bf16x8 __attribute__((ext_vector_type(8)));
typedef unsigned short u16;
typedef unsigned int u32;

__device__ __forceinline__ u16 f2bf(float f) {
  union { float f; unsigned u; } v; v.f = f;
  unsigned r = v.u + 0x7FFFu + ((v.u >> 16) & 1u);
  return (u16)(r >> 16);
}

// UpF[h]: granule byte off = mc*32768 + kh*1024 + m*16, kh in [0,32), m in [0,64)
//   elems e: up[h][kh*8+e][mc*64+m]   (up fp32 [H][256][1024])
__global__ __launch_bounds__(256) void prep_up(const float* __restrict__ src,
                                               u16* __restrict__ dst) {
  __shared__ float tile[64][65];
  const int h = blockIdx.z;
  const int m0 = blockIdx.x * 64, d0 = blockIdx.y * 64;
  const int tr = threadIdx.x >> 6, tc = threadIdx.x & 63;
  const float* s = src + (size_t)h * ND * NM;
#pragma unroll
  for (int i = 0; i < 16; ++i) {
    int r = i * 4 + tr;
    tile[r][tc] = s[(size_t)(d0 + r) * NM + m0 + tc];
  }
  __syncthreads();
  char* dh = (char*)dst + (size_t)h * NM * ND * 2;
#pragma unroll
  for (int g = 0; g < 2; ++g) {
    int gi = g * 256 + threadIdx.x;
    int kh_l = gi >> 6, m_l = gi & 63;
    bf16x8 o;
#pragma unroll
    for (int e = 0; e < 8; ++e) o[e] = (short)f2bf(tile[kh_l * 8 + e][m_l]);
    *(bf16x8*)(dh + (size_t)(m0 >> 6) * 32768 + (size_t)((d0 >> 3) + kh_l) * 1024 + m_l * 16) = o;
  }
}

// DownF[h]: granule byte off = mc*32768 + kh*4096 + d*16, kh in [0,8), d in [0,256)
//   elems e: down[h][mc*64+kh*8+e][d]   (down fp32 [H][1024][256])
__global__ __launch_bounds__(256) void prep_down(const float* __restrict__ src,
                                                 u16* __restrict__ dst) {
  __shared__ float tile[64][65];
  const int h = blockIdx.z;
  const int mc = blockIdx.x, d0 = blockIdx.y * 64;
  const int tr = threadIdx.x >> 6, tc = threadIdx.x & 63;
  const float* s = src + (size_t)h * NM * ND;
#pragma unroll
  for (int i = 0; i < 16; ++i) {
    int r = i * 4 + tr;
    tile[r][tc] = s[(size_t)(mc * 64 + r) * ND + d0 + tc];
  }
  __syncthreads();
  char* dh = (char*)dst + (size_t)h * NM * ND * 2;
#pragma unroll
  for (int g = 0; g < 2; ++g) {
    int gi = g * 256 + threadIdx.x;
    int kh_l = gi >> 6, d_l = gi & 63;
    bf16x8 o;
#pragma unroll
    for (int e = 0; e < 8; ++e) o[e] = (short)f2bf(tile[kh_l * 8 + e][d_l]);
    *(bf16x8*)(dh + (size_t)mc * 32768 + (size_t)kh_l * 4096 + (size_t)(d0 + d_l) * 16) = o;
  }
}

// xp[b][i] = bf16(x[b][perm[i]])
__global__ __launch_bounds__(1024) void permute_x(const float* __restrict__ x,
                                                  const int* __restrict__ perm,
                                                  u16* __restrict__ xp) {
  const int b = blockIdx.x;
  const int t = threadIdx.x;
  const float* xr = x + (size_t)b * 4096;
  int4 p = *(const int4*)(perm + t * 4);
  ushort4 o;
  o.x = f2bf(xr[p.x]); o.y = f2bf(xr[p.y]);
  o.z = f2bf(xr[p.z]); o.w = f2bf(xr[p.w]);
  *(ushort4*)(xp + (size_t)b * 4096 + t * 4) = o;
}

// out[b][j] = out[b][unperm[j]] (in place, one row per block)
__global__ __launch_bounds__(1024) void unpermute_out(float* __restrict__ out,
                                                      const int* __restrict__ unperm) {
  __shared__ float row[4096];
  const int b = blockIdx.x;
  const int t = threadIdx.x;
  float* orow = out + (size_t)b * 4096;
  *(f32x4*)(row + t * 4) = *(const f32x4*)(orow + t * 4);
  __syncthreads();
  int4 u = *(const int4*)(unperm + t * 4);
  f32x4 v;
  v.x = row[u.x]; v.y = row[u.y]; v.z = row[u.z]; v.w = row[u.w];
  *(f32x4*)(orow + t * 4) = v;
}

// 16-wave PRODUCER/CONSUMER MLP (R10 structure: 1024thr, NCH=16, 160KB,
// best measured 404us) with the A-branch made REGISTER-LIGHT. At 1024
// threads, 16 waves must co-reside -> 4 waves/SIMD -> HARD cap 128 unified
// regs/wave (launch_bounds can't lift it; R10/R12's xr[16]=64-arch A-branch
// spilled: VGPR_Count 64, WRITE 335-360MB vs clean 262MB).
//   A-waves (w<8, rtA=w): 16-row strip, 16x16x32 swapped MFMA, xr[8]=32
//     regs (R11's proven-clean loadout), 4 independent pa chains (16 accum):
//     per chunk 32 reads / 32 MFMAs covering 16r x 64m; GELU -> Ps[c]
//     (cvt_pk b64, lane-linear). ~65 regs total.
//   B-waves (w>=8): unchanged R10 (64r x 64d quarter, 32x32x16, ca 64
//     accum, 16 reads / 16 MFMAs per chunk). ~85 regs.
// Trade: A reads all of Us per strip (+128KB/chunk on a <50%-busy LDS pipe)
// for ZERO scratch in the region critical path.
__global__ __launch_bounds__(1024, 4) void mlp_fused(
    const u16* __restrict__ xp,
    const u16* __restrict__ upF,
    const u16* __restrict__ downF,
    float* __restrict__ out) {
  __shared__ __align__(16) u16 Us[2][MB * ND];   // 2x32KB [kh32][m64][8]
  __shared__ __align__(16) u16 Ds[2][ND * MB];   // 2x32KB [kh8][d256][8]
  __shared__ __align__(16) u16 Ps[2][BM * MB];   // 2x16KB [kh8][r128][8]

  const int h   = blockIdx.y;
  const int rb  = blockIdx.x;
  const int tid = threadIdx.x;
  const int w   = tid >> 6;
  const int l   = tid & 63;
  const int row0 = rb * BM;

  const char* upH = (const char*)upF + (size_t)h * NM * ND * 2;
  const char* dnH = (const char*)downF + (size_t)h * NM * ND * 2;

  // ---- prologue: all 16 waves stage Us(0) (2 insts/thread), then barrier
  {
#pragma unroll
    for (int i = 0; i < 2; ++i) {
      int t = i * 1024 + tid;
      __builtin_amdgcn_global_load_lds(
          (const __attribute__((address_space(1))) void*)(upH + (size_t)t * 16),
          (__attribute__((address_space(3))) void*)((char*)&Us[0][0] + (size_t)t * 16),
          16, 0, 0);
    }
  }
  asm volatile("s_waitcnt vmcnt(0)" ::: "memory");
  __builtin_amdgcn_s_barrier();

  if (w < 8) {
    // ================= producer (A): 16x16x32 swapped, 16-row strip ======
    const int rtA = w;            // 16-row strip (8 strips = 128 rows)
    const int ll  = l & 15;       // x-row within strip (frag col)
    const int q   = l >> 4;       // k-quarter (frag k = q*8+e)

    // X fragments: row = row0 + rtA*16 + ll, k(d) = ks*32 + q*8 + e. 32 VGPR.
    bf16x8 xr[8];
    {
      const u16* px = xp + (size_t)(row0 + rtA * 16 + ll) * 4096 + h * ND;
#pragma unroll
      for (int ks = 0; ks < 8; ++ks)
        xr[ks] = *(const bf16x8*)(px + ks * 32 + q * 8);
    }
    // Ps write: value (r = rtA*16+ll, m = mt*16 + q*4 + e) lives at granule
    // (m>>3)*128 + r = (mt*2 + (q>>1))*128 + r, byte (q&1)*8 within granule.
    char* const psW = (char*)&Ps[0][0] +
                      ((size_t)(q >> 1) * 128 + rtA * 16 + ll) * 16 + (q & 1) * 8;

    for (int i = 0; i < NCH; ++i) {
      const int c = i & 1;
      // stage Us(i+1) -> buf c^1 (A-threads: tid in [0,512), 4 insts)
      if (i + 1 < NCH) {
        const char* src = upH + (size_t)(i + 1) * 32768;
#pragma unroll
        for (int j = 0; j < 4; ++j) {
          int t = j * 512 + tid;
          __builtin_amdgcn_global_load_lds(
              (const __attribute__((address_space(1))) void*)(src + (size_t)t * 16),
              (__attribute__((address_space(3))) void*)((char*)&Us[c ^ 1][0] + (size_t)t * 16),
              16, 0, 0);
        }
      }

      // A(i): P[16r x 64m], 4 independent pa chains (one per 16-m tile).
      // av granule for (mt, ks): (ks*4 + q)*64 + mt*16 + ll  -> lane-linear.
      f32x4 pa[4];
#pragma unroll
      for (int mt = 0; mt < 4; ++mt) { f32x4 z = {0.f, 0.f, 0.f, 0.f}; pa[mt] = z; }
      {
        const char* ub = (const char*)&Us[c][0] + ((size_t)q * 64 + ll) * 16;
        __builtin_amdgcn_s_setprio(1);
#pragma unroll
        for (int ks = 0; ks < 8; ++ks)
#pragma unroll
          for (int mt = 0; mt < 4; ++mt) {
            bf16x8 av = *(const bf16x8*)(ub + (size_t)ks * 4096 + mt * 256);
            pa[mt] = __builtin_amdgcn_mfma_f32_16x16x32_bf16(av, xr[ks], pa[mt], 0, 0, 0);
          }
        __builtin_amdgcn_s_setprio(0);
      }

      // gelu -> cvt_pk pack -> 4x ds_write_b64 into Ps[c] (lane-linear)
      // pa[mt][e] = P[r = rtA*16+ll][m = mt*16 + q*4 + e]
#pragma unroll
      for (int mt = 0; mt < 4; ++mt) {
        float gv[4];
#pragma unroll
        for (int e = 0; e < 4; ++e) {
          float v = pa[mt][e];
          float p = __builtin_fmaf(0.1029433f, v * v, 2.3022082f);
          float ex = __builtin_amdgcn_exp2f(v * p);
          float r = __builtin_amdgcn_rcpf(ex + 1.0f);
          gv[e] = __builtin_fmaf(-v, r, v);
        }
        u32 w0, w1;
        asm("v_cvt_pk_bf16_f32 %0, %1, %2" : "=v"(w0) : "v"(gv[0]), "v"(gv[1]));
        asm("v_cvt_pk_bf16_f32 %0, %1, %2" : "=v"(w1) : "v"(gv[2]), "v"(gv[3]));
        uint2 pk; pk.x = w0; pk.y = w1;
        *(uint2*)(psW + (size_t)c * (BM * MB * 2) + (size_t)mt * 4096) = pk;
      }

      __builtin_amdgcn_sched_barrier(0);
      asm volatile("s_waitcnt lgkmcnt(0)" ::: "memory");   // Ps published
      asm volatile("s_waitcnt vmcnt(0)" ::: "memory");     // Us(i+1) landed
      __builtin_amdgcn_s_barrier();
      __builtin_amdgcn_sched_barrier(0);
    }
    // A-waves done (out written by B-waves)
  } else {
    // ================= consumer (B): 32x32x16 (unchanged R10) ============
    const int wb  = w - 8;
    const int rtp = wb & 1;   // 64-row half
    const int dq  = wb >> 1;  // 64-d quarter
    const int tb  = tid - 512;
    const int lo  = l & 31;
    const int hi  = l >> 5;

    f32x16 ca[2][2];   // [rt2][dt] 32x32 tiles: 64r x 64d -> 64 VGPR
#pragma unroll
    for (int rt2 = 0; rt2 < 2; ++rt2)
#pragma unroll
      for (int dt = 0; dt < 2; ++dt)
#pragma unroll
        for (int e = 0; e < 16; ++e)
          ca[rt2][dt][e] = 0.f;

    for (int i = 0; i < NCH; ++i) {
      const int c = i & 1;
      // stage Ds(i) -> buf c (B-threads, 4 insts)
      {
        const char* src = dnH + (size_t)i * 32768;
#pragma unroll
        for (int j = 0; j < 4; ++j) {
          int t = j * 512 + tb;
          __builtin_amdgcn_global_load_lds(
              (const __attribute__((address_space(1))) void*)(src + (size_t)t * 16),
              (__attribute__((address_space(3))) void*)((char*)&Ds[c][0] + (size_t)t * 16),
              16, 0, 0);
        }
      }

      // B(i-1): C += Ps[c^1] @ Ds[c^1]
      if (i > 0) {
        const char* psb = (const char*)&Ps[c ^ 1][0];
        const char* dsb = (const char*)&Ds[c ^ 1][0];
        __builtin_amdgcn_s_setprio(1);
#pragma unroll
        for (int ks = 0; ks < 4; ++ks) {
          const size_t khp = (size_t)(ks * 2 + hi);
          bf16x8 a0 = *(const bf16x8*)(psb + khp * 2048 + (size_t)(rtp * 64 + lo) * 16);
          bf16x8 a1 = *(const bf16x8*)(psb + khp * 2048 + (size_t)(rtp * 64 + 32 + lo) * 16);
#pragma unroll
          for (int dt = 0; dt < 2; ++dt) {
            bf16x8 bv = *(const bf16x8*)(dsb + khp * 4096 + (size_t)(dq * 64 + dt * 32 + lo) * 16);
            ca[0][dt] = __builtin_amdgcn_mfma_f32_32x32x16_bf16(a0, bv, ca[0][dt], 0, 0, 0);
            ca[1][dt] = __builtin_amdgcn_mfma_f32_32x32x16_bf16(a1, bv, ca[1][dt], 0, 0, 0);
          }
        }
        __builtin_amdgcn_s_setprio(0);
      }

      __builtin_amdgcn_sched_barrier(0);
      asm volatile("s_waitcnt vmcnt(0)" ::: "memory");     // Ds(i) landed
      __builtin_amdgcn_s_barrier();
      __builtin_amdgcn_sched_barrier(0);
    }

    // final B(NCH-1): Ps[1], Ds[1]
    {
      const int c = (NCH - 1) & 1;
      const char* psb = (const char*)&Ps[c][0];
      const char* dsb = (const char*)&Ds[c][0];
      __builtin_amdgcn_s_setprio(1);
#pragma unroll
      for (int ks = 0; ks < 4; ++ks) {
        const size_t khp = (size_t)(ks * 2 + hi);
        bf16x8 a0 = *(const bf16x8*)(psb + khp * 2048 + (size_t)(rtp * 64 + lo) * 16);
        bf16x8 a1 = *(const bf16x8*)(psb + khp * 2048 + (size_t)(rtp * 64 + 32 + lo) * 16);
#pragma unroll
        for (int dt = 0; dt < 2; ++dt) {
          bf16x8 bv = *(const bf16x8*)(dsb + khp * 4096 + (size_t)(dq * 64 + dt * 32 + lo) * 16);
          ca[0][dt] = __builtin_amdgcn_mfma_f32_32x32x16_bf16(a0, bv, ca[0][dt], 0, 0, 0);
          ca[1][dt] = __builtin_amdgcn_mfma_f32_32x32x16_bf16(a1, bv, ca[1][dt], 0, 0, 0);
        }
      }
      __builtin_amdgcn_s_setprio(0);
    }

    // epilogue: out[b][h*256+d], coalesced across lanes (32 consecutive d)
    // C-layout 32x32: col d = lo, row = (reg&3) + 8*(reg>>2) + 4*hi.
#pragma unroll
    for (int rt2 = 0; rt2 < 2; ++rt2)
#pragma unroll
      for (int dt = 0; dt < 2; ++dt) {
        const int d = h * ND + dq * 64 + dt * 32 + lo;
#pragma unroll
        for (int reg = 0; reg < 16; ++reg) {
          int r = rtp * 64 + rt2 * 32 + (reg & 3) + 8 * (reg >> 2) + 4 * hi;
          out[(size_t)(row0 + r) * 4096 + d] = ca[rt2][dt][reg];
        }
      }
  }
}

extern "C" void kernel_launch(void* const* d_in, const int* in_sizes, int n_in,
                              void* d_out, int out_size, void* d_ws, size_t ws_size,
                              hipStream_t stream) {
  const float* x    = (const float*)d_in[0];
  const float* up   = (const float*)d_in[1];
  const float* down = (const float*)d_in[2];
  const int* perm   = (const int*)d_in[3];
  const int* unperm = (const int*)d_in[4];
  float* out = (float*)d_out;

  u16* upF   = (u16*)d_ws;                                   // 8 MB
  u16* downF = upF + (size_t)NH * NM * ND;                   // 8 MB
  u16* xp    = downF + (size_t)NH * NM * ND;                 // 128 MB

  // weights -> fragment-granule order (one-time, coalesced tile transposes)
  prep_up<<<dim3(NM / 64, ND / 64, NH), 256, 0, stream>>>(up, upF);
  prep_down<<<dim3(NM / 64, ND / 64, NH), 256, 0, stream>>>(down, downF);
  // xp[b][i] = bf16(x[b][perm[i]])
  permute_x<<<NB, 1024, 0, stream>>>(x, perm, xp);
  // main fused MLP: 1024 thr (8 register-light producers + 8 consumers).
  mlp_fused<<<dim3(NB / BM, NH), 1024, 0, stream>>>(xp, upF, downF, out);
  // in-place feature unpermute
  unpermute_out<<<NB, 1024, 0, stream>>>(out, unperm);
}